// Round 4
// baseline (215.980 us; speedup 1.0000x reference)
//
#include <hip/hip_runtime.h>
#include <hip/hip_bf16.h>

#define N_NODES 50000
#define D_IN 128
#define D_OUT 64
#define N_ETYPES 3
#define E_PER_ETYPE 500000
#define N_EDGES (N_ETYPES * E_PER_ETYPE)
#define CAP1 16   // primary bucket: 32B (ushort) per cell
#define CAP2 30   // spill (deg>16: ~2.6% of cells; P(deg>46)~1e-18)
#define DMAX (CAP1 + CAP2)                      // 46
#define ZROW N_NODES                             // zero feature row (padding target)
#define NB_FEAT ((N_NODES * D_IN / 4) / 256)    // 6250
#define NB_W ((D_IN * D_OUT) / 256)             // 32
#define NZINT4 ((N_ETYPES * N_NODES + 16) / 4)  // 37504 int4 = cnt + qcnt zero region
#define NB_ZCNT ((NZINT4 + 255) / 256)          // 147
#define CHUNK_EDGES 2048                         // 256 thr x 8 edges
#define N_CHUNKS ((N_EDGES + CHUNK_EDGES - 1) / CHUNK_EDGES)   // 733
#define NSLICE 8
#define SLICE_N 6250                             // N_NODES / NSLICE
#define QCAP 196608                              // per-slice queue (mean 187500, +22 sigma)
#define NBLK_PER_SLICE 64                        // binfill grid = 512

typedef __attribute__((ext_vector_type(8))) short short8;
typedef __attribute__((ext_vector_type(4))) float f32x4;

static __device__ __forceinline__ unsigned short f2bf(float f) {
    unsigned int x = __float_as_uint(f);
    unsigned int lsb = (x >> 16) & 1u;
    x += 0x7fffu + lsb;          // round-to-nearest-even
    return (unsigned short)(x >> 16);
}

// Branch-free tanh: ~6 VALU vs ~35 for libm tanhf. |err| ~ 1e-6, budget 0.038.
static __device__ __forceinline__ float fast_tanh(float x) {
    float e = __expf(2.0f * x);
    return 1.0f - 2.0f * __builtin_amdgcn_rcpf(e + 1.0f);
}

static __device__ __forceinline__ short8 as_s8(uint4 u) {
    union { uint4 u; short8 s; } cv; cv.u = u; return cv.s;
}

static __device__ __forceinline__ void accum8(float* ax, uint4 p) {
    ax[0] += __uint_as_float(p.x << 16);
    ax[1] += __uint_as_float(p.x & 0xffff0000u);
    ax[2] += __uint_as_float(p.y << 16);
    ax[3] += __uint_as_float(p.y & 0xffff0000u);
    ax[4] += __uint_as_float(p.z << 16);
    ax[5] += __uint_as_float(p.z & 0xffff0000u);
    ax[6] += __uint_as_float(p.w << 16);
    ax[7] += __uint_as_float(p.w & 0xffff0000u);
}

// Reduce-scatter across the 4 subgroups. Hierarchical ownership: after xor16
// (sub&1)=0 lanes carry dims 0-3, (sub&1)=1 dims 4-7; after xor32 each lane
// holds its 2 owned dims k0, k0+1 with k0 = ((sub&1)<<2)|(sub&2).
static __device__ __forceinline__ float2 rs_reduce(const float* ax, int sub) {
    bool hi = (sub & 1);
    float k0_ = hi ? ax[4] : ax[0], s0_ = hi ? ax[0] : ax[4];
    float k1_ = hi ? ax[5] : ax[1], s1_ = hi ? ax[1] : ax[5];
    float k2_ = hi ? ax[6] : ax[2], s2_ = hi ? ax[2] : ax[6];
    float k3_ = hi ? ax[7] : ax[3], s3_ = hi ? ax[3] : ax[7];
    float h0 = k0_ + __shfl_xor(s0_, 16);
    float h1 = k1_ + __shfl_xor(s1_, 16);
    float h2 = k2_ + __shfl_xor(s2_, 16);
    float h3 = k3_ + __shfl_xor(s3_, 16);
    bool hi2 = (sub & 2);
    float ka = hi2 ? h2 : h0, sa = hi2 ? h0 : h2;
    float kb = hi2 ? h3 : h1, sb = hi2 ? h1 : h3;
    float2 v;
    v.x = ka + __shfl_xor(sa, 32);
    v.y = kb + __shfl_xor(sb, 32);
    return v;
}

// feat (fp32) -> featbf (bf16) + Wt build + zero-row zero + cnt/qcnt zero.
__global__ __launch_bounds__(256) void convert_kernel(
    const float* __restrict__ feat,
    unsigned short* __restrict__ featbf,
    const float* __restrict__ W,
    unsigned short* __restrict__ wtbf,
    int* __restrict__ cnt)
{
    int b = blockIdx.x;
    if (b < NB_FEAT) {
        int i = b * 256 + threadIdx.x;
        const float4* f4 = (const float4*)feat;
        float4 v = f4[i];
        ushort4 o;
        o.x = f2bf(v.x); o.y = f2bf(v.y); o.z = f2bf(v.z); o.w = f2bf(v.w);
        ((ushort4*)featbf)[i] = o;
    } else if (b < NB_FEAT + NB_W) {
        int i = (b - NB_FEAT) * 256 + threadIdx.x;   // 0..8191
        int n = i >> 7;        // output col 0..63
        int k = i & 127;       // input dim 0..127
        wtbf[i] = f2bf(W[k * D_OUT + n]);   // Wt[n][k] = B^T operand layout
    } else if (b == NB_FEAT + NB_W) {
        // zero row ZROW of featbf (gather's padding target)
        if (threadIdx.x < 64)
            ((unsigned int*)(featbf + (size_t)N_NODES * D_IN))[threadIdx.x] = 0;
    } else {
        int i = (b - NB_FEAT - NB_W - 1) * 256 + threadIdx.x;  // int4 index
        if (i < NZINT4) {
            int4 z; z.x = 0; z.y = 0; z.z = 0; z.w = 0;
            ((int4*)cnt)[i] = z;
        }
    }
}

// R11 phase A: read each edge ONCE (nt -> no L2 pollution), pack to one uint
// rec = src(16b) | local_dst(13b) | etype(3b), append to per-slice queue via
// LDS-aggregated block reservation. Traffic: 12MB read + 6MB sequential write
// (vs R9's 54MB of streaming re-reads that evicted the sliced working set --
// the reason WRITE_SIZE stayed at 57MB instead of the predicted 15).
__global__ __launch_bounds__(256) void partition_kernel(
    const int* __restrict__ edge_index,
    unsigned int* __restrict__ queue,
    int* __restrict__ qcnt)
{
    __shared__ int lcnt[NSLICE];
    __shared__ int lbase[NSLICE];
    int tid = threadIdx.x;
    if (tid < NSLICE) lcnt[tid] = 0;
    __syncthreads();

    int e0 = blockIdx.x * CHUNK_EDGES + tid;
    unsigned int rec[CHUNK_EDGES / 256];
    int sl[CHUNK_EDGES / 256], pos[CHUNK_EDGES / 256];
    #pragma unroll
    for (int k = 0; k < CHUNK_EDGES / 256; k++) {
        int e = e0 + k * 256;
        sl[k] = -1;
        if (e < N_EDGES) {
            int t  = e / E_PER_ETYPE;            // const divisor -> magic mul
            int ei = e - t * E_PER_ETYPE;
            const int* base = edge_index + (long long)t * 2 * E_PER_ETYPE;
            int src = __builtin_nontemporal_load(base + ei);
            int dst = __builtin_nontemporal_load(base + E_PER_ETYPE + ei);
            int s = (int)(((unsigned long long)(unsigned)dst * 687195ull) >> 32); // dst/6250
            int ldst = dst - s * SLICE_N;        // 0..6249 (13 bits)
            rec[k] = (unsigned)src | ((unsigned)ldst << 16) | ((unsigned)t << 29);
            sl[k]  = s;
            pos[k] = atomicAdd(&lcnt[s], 1);     // LDS: local position in slice run
        }
    }
    __syncthreads();
    if (tid < NSLICE) lbase[tid] = atomicAdd(&qcnt[tid], lcnt[tid]);
    __syncthreads();
    #pragma unroll
    for (int k = 0; k < CHUNK_EDGES / 256; k++) {
        if (sl[k] >= 0) {
            int p = lbase[sl[k]] + pos[k];
            if (p < QCAP)                         // statically impossible; guards OOB
                queue[sl[k] * QCAP + p] = rec[k];
        }
    }
}

// R11 phase B: slice-local binning. Block (blockIdx&7)=s grid-strides slice
// s's queue (0.75MB, read once, nt). All atomics + bucket/spill/cnt writes
// stay in that XCD's L2-resident 1.8MB slice -> dirty lines written back once.
__global__ __launch_bounds__(256) void binfill_kernel(
    const unsigned int* __restrict__ queue,
    const int* __restrict__ qcnt,
    unsigned short* __restrict__ bucket1,
    unsigned short* __restrict__ spill,
    int* __restrict__ cnt)
{
    int slice = blockIdx.x & 7;
    int blk   = blockIdx.x >> 3;
    int total = qcnt[slice];
    const unsigned int* q = queue + slice * QCAP;
    int sbase = slice * SLICE_N;
    for (int i = blk * 256 + threadIdx.x; i < total; i += NBLK_PER_SLICE * 256) {
        unsigned int r = __builtin_nontemporal_load(q + i);
        int src  = r & 0xFFFF;
        int ldst = (r >> 16) & 0x1FFF;
        int t    = r >> 29;
        int cell = t * N_NODES + sbase + ldst;
        int p = atomicAdd(cnt + cell, 1);
        if (p < CAP1)
            bucket1[cell * CAP1 + p] = (unsigned short)src;
        else if (p < DMAX)
            spill[cell * CAP2 + (p - CAP1)] = (unsigned short)src;
    }
}

// FALLBACK (only if ws_size can't fit the queue): R9 XCD-sliced one-pass fill.
__global__ __launch_bounds__(256) void fill_kernel(
    const int* __restrict__ edge_index,
    unsigned short* __restrict__ bucket1,
    unsigned short* __restrict__ spill,
    int* __restrict__ cnt)
{
    int slice = blockIdx.x & 7;
    int chunk = blockIdx.x >> 3;
    int e0 = chunk * CHUNK_EDGES + threadIdx.x;
    #pragma unroll
    for (int k = 0; k < CHUNK_EDGES / 256; k++) {
        int e = e0 + k * 256;
        if (e < N_EDGES) {
            int t  = e / E_PER_ETYPE;
            int ei = e - t * E_PER_ETYPE;
            const int* base = edge_index + (long long)t * 2 * E_PER_ETYPE;
            int dst = base[E_PER_ETYPE + ei];
            int s = (int)(((unsigned long long)(unsigned)dst * 687195ull) >> 32);
            if (s == slice) {
                int src = base[ei];
                int cell = t * N_NODES + dst;
                int pos = atomicAdd(cnt + cell, 1);
                if (pos < CAP1)
                    bucket1[cell * CAP1 + pos] = (unsigned short)src;
                else if (pos < CAP1 + CAP2)
                    spill[cell * CAP2 + (pos - CAP1)] = (unsigned short)src;
            }
        }
    }
}

// Fused gather + epilogue + MFMA linear. UNCHANGED from R10 (attribution:
// this round's delta belongs to the fill pipeline).
__global__ __launch_bounds__(512) void gather_linear_kernel(
    const float* __restrict__ feat,
    const unsigned short* __restrict__ featbf,
    const unsigned short* __restrict__ wtbf,
    const float* __restrict__ bg,
    const unsigned short* __restrict__ bucket1,
    const unsigned short* __restrict__ spill,
    const int* __restrict__ cnt,
    float* __restrict__ out)
{
    __shared__ unsigned short hsb[16 * 128];   // 4KB bf16 h-tile (full)

    int tid = threadIdx.x;
    int wave = tid >> 6;
    int lane = tid & 63;
    int sub  = lane >> 4;     // subgroup 0..3
    int sl   = lane & 15;     // owns dims [8sl..8sl+7] for gather
    int n0 = blockIdx.x * 16 + wave * 2;   // 3125*16 == 50000 exactly
    int n1 = n0 + 1;

    // Preload deg + up to 46 neighbor indices per etype per node, ZROW-padded.
    int degA[N_ETYPES], degB[N_ETYPES], idxA[N_ETYPES], idxB[N_ETYPES];
    #pragma unroll
    for (int t = 0; t < N_ETYPES; t++) {
        int cell = t * N_NODES + n0;                  // n0 even -> int2 aligned
        int2 dg = *(const int2*)(cnt + cell);
        int la = 0, lb = 0;
        if (lane < CAP1) {
            la = bucket1[cell * CAP1 + lane];
            lb = bucket1[(cell + 1) * CAP1 + lane];
        } else if (lane < DMAX) {
            if (dg.x > CAP1) la = spill[cell * CAP2 + (lane - CAP1)];
            if (dg.y > CAP1) lb = spill[(cell + 1) * CAP2 + (lane - CAP1)];
        }
        int ca = dg.x < DMAX ? dg.x : DMAX;
        int cb = dg.y < DMAX ? dg.y : DMAX;
        idxA[t] = (lane < ca) ? la : ZROW;
        idxB[t] = (lane < cb) ? lb : ZROW;
        degA[t] = dg.x; degB[t] = dg.y;
    }

    // Hierarchical dim ownership (must match rs_reduce): k0 in {0,4,2,6}.
    int k0 = ((sub & 1) << 2) | (sub & 2);
    int p2 = 4 * sl + (k0 >> 1);          // float2 index of owned dim pair
    float2 fA = ((const float2*)feat)[n0 * 64 + p2];
    float2 fB = ((const float2*)feat)[n1 * 64 + p2];

    const uint4* fb4 = (const uint4*)featbf;   // row = 16 uint4 (256B)
    float s0A = 0.0f, s1A = 0.0f, s0B = 0.0f, s1B = 0.0f;

    #pragma unroll
    for (int t = 0; t < N_ETYPES; t++) {
        int da = degA[t] < DMAX ? degA[t] : DMAX;
        int db = degB[t] < DMAX ? degB[t] : DMAX;
        int dm = da > db ? da : db;
        float axA[8], axB[8];
        #pragma unroll
        for (int k = 0; k < 8; k++) { axA[k] = 0.0f; axB[k] = 0.0f; }
        for (int j = 0; j < dm; j += 8) {
            int r0 = j + sub;                    // rows beyond deg -> ZROW
            int r1 = j + 4 + sub;
            int sa0 = __shfl(idxA[t], r0);
            int sa1 = __shfl(idxA[t], r1);
            int sb0 = __shfl(idxB[t], r0);
            int sb1 = __shfl(idxB[t], r1);
            uint4 pa0 = fb4[sa0 * 16 + sl];      // 4 independent 256B gathers
            uint4 pa1 = fb4[sa1 * 16 + sl];
            uint4 pb0 = fb4[sb0 * 16 + sl];
            uint4 pb1 = fb4[sb1 * 16 + sl];
            accum8(axA, pa0); accum8(axA, pa1);  // unconditional: ZROW adds 0
            accum8(axB, pb0); accum8(axB, pb1);
        }
        float2 vA = rs_reduce(axA, sub);
        float2 vB = rs_reduce(axB, sub);
        float invA = __builtin_amdgcn_rcpf((float)(degA[t] > 0 ? degA[t] : 1));
        float invB = __builtin_amdgcn_rcpf((float)(degB[t] > 0 ? degB[t] : 1));
        s0A += fast_tanh(vA.x * invA);
        s1A += fast_tanh(vA.y * invA);
        s0B += fast_tanh(vB.x * invB);
        s1B += fast_tanh(vB.y * invB);
    }

    // Epilogue h-compute + XOR-swizzled bf16 LDS store.
    float hxA = fast_tanh(fA.x + 0.5f * s0A);
    float hyA = fast_tanh(fA.y + 0.5f * s1A);
    float hxB = fast_tanh(fB.x + 0.5f * s0B);
    float hyB = fast_tanh(fB.y + 0.5f * s1B);
    unsigned int hpA = (unsigned int)f2bf(hxA) | ((unsigned int)f2bf(hyA) << 16);
    unsigned int hpB = (unsigned int)f2bf(hxB) | ((unsigned int)f2bf(hyB) << 16);
    int colb = 16 * sl + 2 * k0;
    int rA = wave * 2, rB = rA + 1;
    ((unsigned int*)hsb)[(rA * 256 + (colb ^ ((rA & 7) << 4))) >> 2] = hpA;
    ((unsigned int*)hsb)[(rB * 256 + (colb ^ ((rB & 7) << 4))) >> 2] = hpB;

    // Waves 0..3: prefetch B-frags + bias from global BEFORE the barrier.
    uint4 b0 = {0,0,0,0}, b1 = {0,0,0,0}, b2 = {0,0,0,0}, b3 = {0,0,0,0};
    float bias = 0.0f;
    if (wave < 4) {
        int nrow = wave * 16 + sl;                   // output col 0..63
        const uint4* wt4 = (const uint4*)wtbf;       // Wt[n][k] bf16, 16 uint4/row
        b0 = wt4[nrow * 16 +  0 + sub];
        b1 = wt4[nrow * 16 +  4 + sub];
        b2 = wt4[nrow * 16 +  8 + sub];
        b3 = wt4[nrow * 16 + 12 + sub];
        bias = bg[nrow];
    }
    __syncthreads();

    if (wave < 4) {
        // A-frag: lane l -> h row (l&15), k = ks*32 + sub*8 .. +7 (swizzled)
        int row = sl;
        int rbase = row * 256;
        int rx = (row & 7) << 4;
        const uint4* h4 = (const uint4*)hsb;
        uint4 a0 = h4[(rbase + (( 0 + sub * 16) ^ rx)) >> 4];
        uint4 a1 = h4[(rbase + (( 64 + sub * 16) ^ rx)) >> 4];
        uint4 a2 = h4[(rbase + ((128 + sub * 16) ^ rx)) >> 4];
        uint4 a3 = h4[(rbase + ((192 + sub * 16) ^ rx)) >> 4];

        f32x4 c = {bias, bias, bias, bias};          // bias via C-init
        c = __builtin_amdgcn_mfma_f32_16x16x32_bf16(as_s8(a0), as_s8(b0), c, 0, 0, 0);
        c = __builtin_amdgcn_mfma_f32_16x16x32_bf16(as_s8(a1), as_s8(b1), c, 0, 0, 0);
        c = __builtin_amdgcn_mfma_f32_16x16x32_bf16(as_s8(a2), as_s8(b2), c, 0, 0, 0);
        c = __builtin_amdgcn_mfma_f32_16x16x32_bf16(as_s8(a3), as_s8(b3), c, 0, 0, 0);

        // C/D layout (m89-verified): col = lane&15, row = sub*4 + i.
        #pragma unroll
        for (int i = 0; i < 4; i++) {
            int orow = sub * 4 + i;
            out[(blockIdx.x * 16 + orow) * 64 + wave * 16 + sl] = c[i];
        }
    }
}

extern "C" void kernel_launch(void* const* d_in, const int* in_sizes, int n_in,
                              void* d_out, int out_size, void* d_ws, size_t ws_size,
                              hipStream_t stream) {
    const float* feat = (const float*)d_in[0];
    const float* W    = (const float*)d_in[1];
    const float* b    = (const float*)d_in[2];
    const int* edge_index = (const int*)d_in[3];
    float* out = (float*)d_out;

    size_t featbf_bytes  = (size_t)(N_NODES + 1) * D_IN * sizeof(unsigned short);      // 12,800,256
    size_t bucket1_bytes = (size_t)N_ETYPES * N_NODES * CAP1 * sizeof(unsigned short); //  4,800,000
    size_t spill_bytes   = (size_t)N_ETYPES * N_NODES * CAP2 * sizeof(unsigned short); //  9,000,000
    size_t cnt_bytes     = (size_t)(N_ETYPES * N_NODES + 16) * sizeof(int);            //    600,064 (cnt + qcnt)
    size_t wtbf_bytes    = (size_t)D_IN * D_OUT * sizeof(unsigned short);              //     16,384
    size_t base_bytes    = featbf_bytes + bucket1_bytes + spill_bytes + cnt_bytes + wtbf_bytes; // 27,216,704
    size_t queue_bytes   = (size_t)NSLICE * QCAP * sizeof(unsigned int);               //  6,291,456
    if (ws_size < base_bytes)
        return;  // sentinel: out stays 0 (absmax would read 1.898)
    bool twophase = (ws_size >= base_bytes + queue_bytes);

    unsigned short* featbf  = (unsigned short*)d_ws;
    unsigned short* bucket1 = (unsigned short*)((char*)d_ws + featbf_bytes);
    unsigned short* spill   = (unsigned short*)((char*)d_ws + featbf_bytes + bucket1_bytes);
    int* cnt = (int*)((char*)d_ws + featbf_bytes + bucket1_bytes + spill_bytes);
    int* qcnt = cnt + N_ETYPES * N_NODES;        // 8 ints, zeroed with cnt
    unsigned short* wtbf = (unsigned short*)((char*)d_ws + featbf_bytes + bucket1_bytes
                                             + spill_bytes + cnt_bytes);
    unsigned int* queue = (unsigned int*)((char*)d_ws + base_bytes);

    convert_kernel<<<NB_FEAT + NB_W + 1 + NB_ZCNT, 256, 0, stream>>>(
        feat, featbf, W, wtbf, cnt);

    if (twophase) {
        partition_kernel<<<N_CHUNKS, 256, 0, stream>>>(edge_index, queue, qcnt);
        binfill_kernel<<<NSLICE * NBLK_PER_SLICE, 256, 0, stream>>>(
            queue, qcnt, bucket1, spill, cnt);
    } else {
        fill_kernel<<<N_CHUNKS * 8, 256, 0, stream>>>(edge_index, bucket1, spill, cnt);
    }

    gather_linear_kernel<<<N_NODES / 16, 512, 0, stream>>>(
        feat, featbf, wtbf, b, bucket1, spill, cnt, out);
}

// Round 6
// 210.684 us; speedup vs baseline: 1.0251x; 1.0251x over previous
//
#include <hip/hip_runtime.h>
#include <hip/hip_bf16.h>

#define N_NODES 50000
#define D_IN 128
#define D_OUT 64
#define N_ETYPES 3
#define E_PER_ETYPE 500000
#define N_EDGES (N_ETYPES * E_PER_ETYPE)
#define CAP1 16   // primary bucket: 32B (ushort) per cell
#define CAP2 30   // spill (deg>16: ~2.6% of cells; P(deg>46)~1e-18)
#define DMAX (CAP1 + CAP2)                      // 46
#define ZROW N_NODES                             // zero feature row (padding target)
#define NB_FEAT ((N_NODES * D_IN / 4) / 256)    // 6250
#define NB_W ((D_IN * D_OUT) / 256)             // 32
#define NZINT4 ((N_ETYPES * N_NODES + 16) / 4)  // 37504 int4 = cnt + qcnt zero region
#define NB_ZCNT ((NZINT4 + 255) / 256)          // 147
#define CHUNK_EDGES 2048                         // 256 thr x 8 edges
#define N_CHUNKS ((N_EDGES + CHUNK_EDGES - 1) / CHUNK_EDGES)   // 733
#define NSLICE 8
#define SLICE_N 6250                             // N_NODES / NSLICE
#define QCAP 196608                              // (dead path, kept for TU pinning)
#define NBLK_PER_SLICE 64

typedef __attribute__((ext_vector_type(8))) short short8;
typedef __attribute__((ext_vector_type(4))) float f32x4;

static __device__ __forceinline__ unsigned short f2bf(float f) {
    unsigned int x = __float_as_uint(f);
    unsigned int lsb = (x >> 16) & 1u;
    x += 0x7fffu + lsb;          // round-to-nearest-even
    return (unsigned short)(x >> 16);
}

// Branch-free tanh: ~6 VALU vs ~35 for libm tanhf. |err| ~ 1e-6, budget 0.038.
static __device__ __forceinline__ float fast_tanh(float x) {
    float e = __expf(2.0f * x);
    return 1.0f - 2.0f * __builtin_amdgcn_rcpf(e + 1.0f);
}

static __device__ __forceinline__ short8 as_s8(uint4 u) {
    union { uint4 u; short8 s; } cv; cv.u = u; return cv.s;
}

static __device__ __forceinline__ void accum8(float* ax, uint4 p) {
    ax[0] += __uint_as_float(p.x << 16);
    ax[1] += __uint_as_float(p.x & 0xffff0000u);
    ax[2] += __uint_as_float(p.y << 16);
    ax[3] += __uint_as_float(p.y & 0xffff0000u);
    ax[4] += __uint_as_float(p.z << 16);
    ax[5] += __uint_as_float(p.z & 0xffff0000u);
    ax[6] += __uint_as_float(p.w << 16);
    ax[7] += __uint_as_float(p.w & 0xffff0000u);
}

// Reduce-scatter across the 4 subgroups. Hierarchical ownership: after xor16
// (sub&1)=0 lanes carry dims 0-3, (sub&1)=1 dims 4-7; after xor32 each lane
// holds its 2 owned dims k0, k0+1 with k0 = ((sub&1)<<2)|(sub&2).
static __device__ __forceinline__ float2 rs_reduce(const float* ax, int sub) {
    bool hi = (sub & 1);
    float k0_ = hi ? ax[4] : ax[0], s0_ = hi ? ax[0] : ax[4];
    float k1_ = hi ? ax[5] : ax[1], s1_ = hi ? ax[1] : ax[5];
    float k2_ = hi ? ax[6] : ax[2], s2_ = hi ? ax[2] : ax[6];
    float k3_ = hi ? ax[7] : ax[3], s3_ = hi ? ax[3] : ax[7];
    float h0 = k0_ + __shfl_xor(s0_, 16);
    float h1 = k1_ + __shfl_xor(s1_, 16);
    float h2 = k2_ + __shfl_xor(s2_, 16);
    float h3 = k3_ + __shfl_xor(s3_, 16);
    bool hi2 = (sub & 2);
    float ka = hi2 ? h2 : h0, sa = hi2 ? h0 : h2;
    float kb = hi2 ? h3 : h1, sb = hi2 ? h1 : h3;
    float2 v;
    v.x = ka + __shfl_xor(sa, 32);
    v.y = kb + __shfl_xor(sb, 32);
    return v;
}

// feat (fp32) -> featbf (bf16) + Wt build + zero-row zero + cnt/qcnt zero.
__global__ __launch_bounds__(256) void convert_kernel(
    const float* __restrict__ feat,
    unsigned short* __restrict__ featbf,
    const float* __restrict__ W,
    unsigned short* __restrict__ wtbf,
    int* __restrict__ cnt)
{
    int b = blockIdx.x;
    if (b < NB_FEAT) {
        int i = b * 256 + threadIdx.x;
        const float4* f4 = (const float4*)feat;
        float4 v = f4[i];
        ushort4 o;
        o.x = f2bf(v.x); o.y = f2bf(v.y); o.z = f2bf(v.z); o.w = f2bf(v.w);
        ((ushort4*)featbf)[i] = o;
    } else if (b < NB_FEAT + NB_W) {
        int i = (b - NB_FEAT) * 256 + threadIdx.x;   // 0..8191
        int n = i >> 7;        // output col 0..63
        int k = i & 127;       // input dim 0..127
        wtbf[i] = f2bf(W[k * D_OUT + n]);   // Wt[n][k] = B^T operand layout
    } else if (b == NB_FEAT + NB_W) {
        // zero row ZROW of featbf (gather's padding target)
        if (threadIdx.x < 64)
            ((unsigned int*)(featbf + (size_t)N_NODES * D_IN))[threadIdx.x] = 0;
    } else {
        int i = (b - NB_FEAT - NB_W - 1) * 256 + threadIdx.x;  // int4 index
        if (i < NZINT4) {
            int4 z; z.x = 0; z.y = 0; z.z = 0; z.w = 0;
            ((int4*)cnt)[i] = z;
        }
    }
}

// R12 (fixed compile): one-pass XCD-sliced fill with NONTEMPORAL streaming
// reads. R3's counters showed the true mechanism: the 8x edge scans ALLOCATE
// in L2 and evict the dirty sliced payload (WRITE 57MB = 16x payload, FETCH
// 47MB of re-fetches). nt loads keep scan lines out of L2 -> each XCD's 1.8MB
// bucket slice + 75KB cnt stays resident, dirty lines written back once.
__global__ __launch_bounds__(256) void fill_kernel(
    const int* __restrict__ edge_index,
    unsigned short* __restrict__ bucket1,
    unsigned short* __restrict__ spill,
    int* __restrict__ cnt)
{
    int slice = blockIdx.x & 7;
    int chunk = blockIdx.x >> 3;
    int e0 = chunk * CHUNK_EDGES + threadIdx.x;
    #pragma unroll
    for (int k = 0; k < CHUNK_EDGES / 256; k++) {
        int e = e0 + k * 256;
        if (e < N_EDGES) {
            int t  = e / E_PER_ETYPE;            // const divisor -> magic mul
            int ei = e - t * E_PER_ETYPE;
            const int* base = edge_index + (long long)t * 2 * E_PER_ETYPE;
            int dst = __builtin_nontemporal_load(base + E_PER_ETYPE + ei);   // stream, no L2 alloc
            int s = (int)(((unsigned long long)(unsigned)dst * 687195ull) >> 32); // dst/6250
            if (s == slice) {
                int src = __builtin_nontemporal_load(base + ei);             // stream, no L2 alloc
                int cell = t * N_NODES + dst;
                int pos = atomicAdd(cnt + cell, 1);
                if (pos < CAP1)
                    bucket1[cell * CAP1 + pos] = (unsigned short)src;
                else if (pos < CAP1 + CAP2)
                    spill[cell * CAP2 + (pos - CAP1)] = (unsigned short)src;
            }
        }
    }
}

// DEAD CODE, kept compiled on purpose: R11's partition/binfill. Removing them
// would re-roll gather_linear's codegen dice (rule: co-compiled kernels share
// regalloc context; the current TU gives gather 52 VGPR / 61.5us, better than
// the R10 TU's schedule). Not launched.
__global__ __launch_bounds__(256) void partition_kernel(
    const int* __restrict__ edge_index,
    unsigned int* __restrict__ queue,
    int* __restrict__ qcnt)
{
    __shared__ int lcnt[NSLICE];
    __shared__ int lbase[NSLICE];
    int tid = threadIdx.x;
    if (tid < NSLICE) lcnt[tid] = 0;
    __syncthreads();
    int e0 = blockIdx.x * CHUNK_EDGES + tid;
    unsigned int rec[CHUNK_EDGES / 256];
    int sl[CHUNK_EDGES / 256], pos[CHUNK_EDGES / 256];
    #pragma unroll
    for (int k = 0; k < CHUNK_EDGES / 256; k++) {
        int e = e0 + k * 256;
        sl[k] = -1;
        if (e < N_EDGES) {
            int t  = e / E_PER_ETYPE;
            int ei = e - t * E_PER_ETYPE;
            const int* base = edge_index + (long long)t * 2 * E_PER_ETYPE;
            int src = __builtin_nontemporal_load(base + ei);
            int dst = __builtin_nontemporal_load(base + E_PER_ETYPE + ei);
            int s = (int)(((unsigned long long)(unsigned)dst * 687195ull) >> 32);
            int ldst = dst - s * SLICE_N;
            rec[k] = (unsigned)src | ((unsigned)ldst << 16) | ((unsigned)t << 29);
            sl[k]  = s;
            pos[k] = atomicAdd(&lcnt[s], 1);
        }
    }
    __syncthreads();
    if (tid < NSLICE) lbase[tid] = atomicAdd(&qcnt[tid], lcnt[tid]);
    __syncthreads();
    #pragma unroll
    for (int k = 0; k < CHUNK_EDGES / 256; k++) {
        if (sl[k] >= 0) {
            int p = lbase[sl[k]] + pos[k];
            if (p < QCAP)
                queue[sl[k] * QCAP + p] = rec[k];
        }
    }
}

__global__ __launch_bounds__(256) void binfill_kernel(
    const unsigned int* __restrict__ queue,
    const int* __restrict__ qcnt,
    unsigned short* __restrict__ bucket1,
    unsigned short* __restrict__ spill,
    int* __restrict__ cnt)
{
    int slice = blockIdx.x & 7;
    int blk   = blockIdx.x >> 3;
    int total = qcnt[slice];
    const unsigned int* q = queue + slice * QCAP;
    int sbase = slice * SLICE_N;
    for (int i = blk * 256 + threadIdx.x; i < total; i += NBLK_PER_SLICE * 256) {
        unsigned int r = __builtin_nontemporal_load(q + i);
        int src  = r & 0xFFFF;
        int ldst = (r >> 16) & 0x1FFF;
        int t    = r >> 29;
        int cell = t * N_NODES + sbase + ldst;
        int p = atomicAdd(cnt + cell, 1);
        if (p < CAP1)
            bucket1[cell * CAP1 + p] = (unsigned short)src;
        else if (p < DMAX)
            spill[cell * CAP2 + (p - CAP1)] = (unsigned short)src;
    }
}

// Fused gather + epilogue + MFMA linear. R12 deltas (small, principled):
//  - bucket/spill/cnt preloads nontemporal: read-exactly-once data, stop it
//    evicting featbf from L2 (featbf rows are re-read ~30x each by gathers).
//    cnt pair loaded as one nt long long (8B-aligned: n0 even, base 16B-aligned)
//    -- __builtin_nontemporal_load rejects HIP's class-type int2 (R4 compile fail).
//  - residual read from featbf (bf16, L2-hot, 4B/lane) instead of fp32 feat
//    (8B/lane, cold): halves that stream; added err <= |f|*2^-9*sech^2 ~ 0.002
__global__ __launch_bounds__(512) void gather_linear_kernel(
    const float* __restrict__ feat,
    const unsigned short* __restrict__ featbf,
    const unsigned short* __restrict__ wtbf,
    const float* __restrict__ bg,
    const unsigned short* __restrict__ bucket1,
    const unsigned short* __restrict__ spill,
    const int* __restrict__ cnt,
    float* __restrict__ out)
{
    __shared__ unsigned short hsb[16 * 128];   // 4KB bf16 h-tile (full)

    int tid = threadIdx.x;
    int wave = tid >> 6;
    int lane = tid & 63;
    int sub  = lane >> 4;     // subgroup 0..3
    int sl   = lane & 15;     // owns dims [8sl..8sl+7] for gather
    int n0 = blockIdx.x * 16 + wave * 2;   // 3125*16 == 50000 exactly
    int n1 = n0 + 1;

    // Preload deg + up to 46 neighbor indices per etype per node, ZROW-padded.
    int degA[N_ETYPES], degB[N_ETYPES], idxA[N_ETYPES], idxB[N_ETYPES];
    #pragma unroll
    for (int t = 0; t < N_ETYPES; t++) {
        int cell = t * N_NODES + n0;                  // n0 even -> 8B aligned pair
        unsigned long long dgp = __builtin_nontemporal_load(
            (const unsigned long long*)(cnt + cell));
        int dgx = (int)(dgp & 0xffffffffull);
        int dgy = (int)(dgp >> 32);
        int la = 0, lb = 0;
        if (lane < CAP1) {
            la = __builtin_nontemporal_load(bucket1 + cell * CAP1 + lane);
            lb = __builtin_nontemporal_load(bucket1 + (cell + 1) * CAP1 + lane);
        } else if (lane < DMAX) {
            if (dgx > CAP1) la = __builtin_nontemporal_load(spill + cell * CAP2 + (lane - CAP1));
            if (dgy > CAP1) lb = __builtin_nontemporal_load(spill + (cell + 1) * CAP2 + (lane - CAP1));
        }
        int ca = dgx < DMAX ? dgx : DMAX;
        int cb = dgy < DMAX ? dgy : DMAX;
        idxA[t] = (lane < ca) ? la : ZROW;
        idxB[t] = (lane < cb) ? lb : ZROW;
        degA[t] = dgx; degB[t] = dgy;
    }

    // Hierarchical dim ownership (must match rs_reduce): k0 in {0,4,2,6}.
    int k0 = ((sub & 1) << 2) | (sub & 2);
    int p2 = 4 * sl + (k0 >> 1);          // uint index of owned bf16 dim pair
    // Residual loads hoisted (overlap the gather); bf16 pair from hot featbf.
    unsigned int rfA = ((const unsigned int*)featbf)[n0 * 64 + p2];
    unsigned int rfB = ((const unsigned int*)featbf)[n1 * 64 + p2];

    const uint4* fb4 = (const uint4*)featbf;   // row = 16 uint4 (256B)
    float s0A = 0.0f, s1A = 0.0f, s0B = 0.0f, s1B = 0.0f;

    #pragma unroll
    for (int t = 0; t < N_ETYPES; t++) {
        int da = degA[t] < DMAX ? degA[t] : DMAX;
        int db = degB[t] < DMAX ? degB[t] : DMAX;
        int dm = da > db ? da : db;
        float axA[8], axB[8];
        #pragma unroll
        for (int k = 0; k < 8; k++) { axA[k] = 0.0f; axB[k] = 0.0f; }
        for (int j = 0; j < dm; j += 8) {
            int r0 = j + sub;                    // rows beyond deg -> ZROW
            int r1 = j + 4 + sub;
            int sa0 = __shfl(idxA[t], r0);
            int sa1 = __shfl(idxA[t], r1);
            int sb0 = __shfl(idxB[t], r0);
            int sb1 = __shfl(idxB[t], r1);
            uint4 pa0 = fb4[sa0 * 16 + sl];      // 4 independent 256B gathers
            uint4 pa1 = fb4[sa1 * 16 + sl];
            uint4 pb0 = fb4[sb0 * 16 + sl];
            uint4 pb1 = fb4[sb1 * 16 + sl];
            accum8(axA, pa0); accum8(axA, pa1);  // unconditional: ZROW adds 0
            accum8(axB, pb0); accum8(axB, pb1);
        }
        float2 vA = rs_reduce(axA, sub);
        float2 vB = rs_reduce(axB, sub);
        float invA = __builtin_amdgcn_rcpf((float)(degA[t] > 0 ? degA[t] : 1));
        float invB = __builtin_amdgcn_rcpf((float)(degB[t] > 0 ? degB[t] : 1));
        s0A += fast_tanh(vA.x * invA);
        s1A += fast_tanh(vA.y * invA);
        s0B += fast_tanh(vB.x * invB);
        s1B += fast_tanh(vB.y * invB);
    }

    // Epilogue h-compute + XOR-swizzled bf16 LDS store.
    float fAx = __uint_as_float(rfA << 16);
    float fAy = __uint_as_float(rfA & 0xffff0000u);
    float fBx = __uint_as_float(rfB << 16);
    float fBy = __uint_as_float(rfB & 0xffff0000u);
    float hxA = fast_tanh(fAx + 0.5f * s0A);
    float hyA = fast_tanh(fAy + 0.5f * s1A);
    float hxB = fast_tanh(fBx + 0.5f * s0B);
    float hyB = fast_tanh(fBy + 0.5f * s1B);
    unsigned int hpA = (unsigned int)f2bf(hxA) | ((unsigned int)f2bf(hyA) << 16);
    unsigned int hpB = (unsigned int)f2bf(hxB) | ((unsigned int)f2bf(hyB) << 16);
    int colb = 16 * sl + 2 * k0;
    int rA = wave * 2, rB = rA + 1;
    ((unsigned int*)hsb)[(rA * 256 + (colb ^ ((rA & 7) << 4))) >> 2] = hpA;
    ((unsigned int*)hsb)[(rB * 256 + (colb ^ ((rB & 7) << 4))) >> 2] = hpB;

    // Waves 0..3: prefetch B-frags + bias from global BEFORE the barrier.
    uint4 b0 = {0,0,0,0}, b1 = {0,0,0,0}, b2 = {0,0,0,0}, b3 = {0,0,0,0};
    float bias = 0.0f;
    if (wave < 4) {
        int nrow = wave * 16 + sl;                   // output col 0..63
        const uint4* wt4 = (const uint4*)wtbf;       // Wt[n][k] bf16, 16 uint4/row
        b0 = wt4[nrow * 16 +  0 + sub];
        b1 = wt4[nrow * 16 +  4 + sub];
        b2 = wt4[nrow * 16 +  8 + sub];
        b3 = wt4[nrow * 16 + 12 + sub];
        bias = bg[nrow];
    }
    __syncthreads();

    if (wave < 4) {
        // A-frag: lane l -> h row (l&15), k = ks*32 + sub*8 .. +7 (swizzled)
        int row = sl;
        int rbase = row * 256;
        int rx = (row & 7) << 4;
        const uint4* h4 = (const uint4*)hsb;
        uint4 a0 = h4[(rbase + (( 0 + sub * 16) ^ rx)) >> 4];
        uint4 a1 = h4[(rbase + (( 64 + sub * 16) ^ rx)) >> 4];
        uint4 a2 = h4[(rbase + ((128 + sub * 16) ^ rx)) >> 4];
        uint4 a3 = h4[(rbase + ((192 + sub * 16) ^ rx)) >> 4];

        f32x4 c = {bias, bias, bias, bias};          // bias via C-init
        c = __builtin_amdgcn_mfma_f32_16x16x32_bf16(as_s8(a0), as_s8(b0), c, 0, 0, 0);
        c = __builtin_amdgcn_mfma_f32_16x16x32_bf16(as_s8(a1), as_s8(b1), c, 0, 0, 0);
        c = __builtin_amdgcn_mfma_f32_16x16x32_bf16(as_s8(a2), as_s8(b2), c, 0, 0, 0);
        c = __builtin_amdgcn_mfma_f32_16x16x32_bf16(as_s8(a3), as_s8(b3), c, 0, 0, 0);

        // C/D layout (m89-verified): col = lane&15, row = sub*4 + i.
        #pragma unroll
        for (int i = 0; i < 4; i++) {
            int orow = sub * 4 + i;
            out[(blockIdx.x * 16 + orow) * 64 + wave * 16 + sl] = c[i];
        }
    }
}

extern "C" void kernel_launch(void* const* d_in, const int* in_sizes, int n_in,
                              void* d_out, int out_size, void* d_ws, size_t ws_size,
                              hipStream_t stream) {
    const float* feat = (const float*)d_in[0];
    const float* W    = (const float*)d_in[1];
    const float* b    = (const float*)d_in[2];
    const int* edge_index = (const int*)d_in[3];
    float* out = (float*)d_out;

    size_t featbf_bytes  = (size_t)(N_NODES + 1) * D_IN * sizeof(unsigned short);      // 12,800,256
    size_t bucket1_bytes = (size_t)N_ETYPES * N_NODES * CAP1 * sizeof(unsigned short); //  4,800,000
    size_t spill_bytes   = (size_t)N_ETYPES * N_NODES * CAP2 * sizeof(unsigned short); //  9,000,000
    size_t cnt_bytes     = (size_t)(N_ETYPES * N_NODES + 16) * sizeof(int);            //    600,064 (cnt + qcnt)
    size_t wtbf_bytes    = (size_t)D_IN * D_OUT * sizeof(unsigned short);              //     16,384
    size_t base_bytes    = featbf_bytes + bucket1_bytes + spill_bytes + cnt_bytes + wtbf_bytes; // 27,216,704
    if (ws_size < base_bytes)
        return;  // sentinel: out stays 0 (absmax would read 1.898)

    unsigned short* featbf  = (unsigned short*)d_ws;
    unsigned short* bucket1 = (unsigned short*)((char*)d_ws + featbf_bytes);
    unsigned short* spill   = (unsigned short*)((char*)d_ws + featbf_bytes + bucket1_bytes);
    int* cnt = (int*)((char*)d_ws + featbf_bytes + bucket1_bytes + spill_bytes);
    unsigned short* wtbf = (unsigned short*)((char*)d_ws + featbf_bytes + bucket1_bytes
                                             + spill_bytes + cnt_bytes);

    convert_kernel<<<NB_FEAT + NB_W + 1 + NB_ZCNT, 256, 0, stream>>>(
        feat, featbf, W, wtbf, cnt);

    // One-pass XCD-sliced fill with nt streaming reads (R11 queue path retired:
    // it regressed; kernels kept compiled only to pin gather's codegen).
    fill_kernel<<<N_CHUNKS * 8, 256, 0, stream>>>(edge_index, bucket1, spill, cnt);

    gather_linear_kernel<<<N_NODES / 16, 512, 0, stream>>>(
        feat, featbf, wtbf, b, bucket1, spill, cnt, out);
}